// Round 1
// baseline (378.822 us; speedup 1.0000x reference)
//
#include <hip/hip_runtime.h>

#define NC_MEM 64
#define NC_IMG 64
#define NC     128
#define NBLK   3
#define B_     32
#define H_     64
#define W_     96
#define HW_    (H_ * W_)      // 6144
#define M_     32
#define P_TILE 64
#define NTILES (HW_ / P_TILE) // 96

// d_ws float layout
#define WT_OFF 0                       // 3*128*128 floats (W transposed: [l][c][o])
#define XF_OFF (NBLK * NC * NC)        // 32*16 floats
#define UM_OFF (XF_OFF + B_ * 16)     // 32 floats (0.0 / 1.0)

// ---------------------------------------------------------------------------
// Prep: per-batch 4x4 inverse + xf = cur @ inv(safe_prev); decode use_memory.
// use_memory arrives either as 1-byte bool or 4-byte int32 — detect at runtime
// from the byte pattern of the first 32 bytes (int32 layout has zeros at all
// byte positions not divisible by 4).
// ---------------------------------------------------------------------------
__global__ void prep_xf(const float* __restrict__ prev_ext,
                        const float* __restrict__ cur_ext,
                        const int* __restrict__ mem_idx,
                        const unsigned char* __restrict__ um_raw,
                        float* __restrict__ ws) {
    int b = threadIdx.x;
    if (b >= B_) return;

    bool is_bool = false;
    for (int i = 0; i < 32; ++i)
        if ((i & 3) && um_raw[i]) is_bool = true;
    bool um = is_bool ? (um_raw[b] != 0) : (((const int*)um_raw)[b] != 0);

    int mi = mem_idx[b];
    float A[4][4], inv[4][4];
    for (int i = 0; i < 4; ++i)
        for (int j = 0; j < 4; ++j) {
            A[i][j]   = um ? prev_ext[mi * 16 + i * 4 + j] : (i == j ? 1.f : 0.f);
            inv[i][j] = (i == j) ? 1.f : 0.f;
        }
    // Gauss-Jordan with partial pivoting
    for (int col = 0; col < 4; ++col) {
        int piv = col;
        float best = fabsf(A[col][col]);
        for (int r = col + 1; r < 4; ++r) {
            float v = fabsf(A[r][col]);
            if (v > best) { best = v; piv = r; }
        }
        if (piv != col) {
            for (int j = 0; j < 4; ++j) {
                float t = A[col][j]; A[col][j] = A[piv][j]; A[piv][j] = t;
                t = inv[col][j]; inv[col][j] = inv[piv][j]; inv[piv][j] = t;
            }
        }
        float d = 1.0f / A[col][col];
        for (int j = 0; j < 4; ++j) { A[col][j] *= d; inv[col][j] *= d; }
        for (int r = 0; r < 4; ++r) {
            if (r == col) continue;
            float f = A[r][col];
            for (int j = 0; j < 4; ++j) {
                A[r][j] -= f * A[col][j];
                inv[r][j] -= f * inv[col][j];
            }
        }
    }
    // xf = cur_ext[b] @ inv
    for (int i = 0; i < 4; ++i)
        for (int j = 0; j < 4; ++j) {
            float s = 0.f;
            for (int k = 0; k < 4; ++k)
                s += cur_ext[b * 16 + i * 4 + k] * inv[k][j];
            ws[XF_OFF + b * 16 + i * 4 + j] = s;
        }
    ws[UM_OFF + b] = um ? 1.f : 0.f;
}

// ---------------------------------------------------------------------------
// Transpose Ws[l][o][c] -> Wt[l][c][o] so the main loop loads 8 consecutive
// output-channel weights per c as two dwordx4.
// ---------------------------------------------------------------------------
__global__ void transpose_w(const float* __restrict__ Ws, float* __restrict__ ws) {
    int idx = blockIdx.x * blockDim.x + threadIdx.x;
    if (idx >= NBLK * NC * NC) return;
    int l = idx / (NC * NC);
    int r = idx % (NC * NC);
    int o = r / NC, c = r % NC;
    ws[WT_OFF + l * NC * NC + c * NC + o] = Ws[idx];
}

// ---------------------------------------------------------------------------
// Fused main: stage x tile (128 ch x 64 px) in LDS, FTL in place, 3 dense
// layers (ping-pong LDS), layer-2 computes only out-channels 64..127 and
// writes straight to global from registers.
// ---------------------------------------------------------------------------
__global__ __launch_bounds__(256)
void fused_main(const float* __restrict__ img, const float* __restrict__ mem,
                const int* __restrict__ mem_idx, const float* __restrict__ bs,
                const float* __restrict__ ws, float* __restrict__ out) {
    __shared__ float xb[2][NC][P_TILE]; // 64 KB

    const int t   = threadIdx.x;
    const int b   = blockIdx.y;
    const int hw0 = blockIdx.x * P_TILE;

    const float um = ws[UM_OFF + b];
    const bool umb = (um != 0.f);
    const float* Wt = ws + WT_OFF;

    // ---- stage ----
    const int px = t & 63;
    const int cb = t >> 6;
    const int mi = mem_idx[b];
    const float* memb = mem + (size_t)mi * (NC_MEM * HW_) + hw0;
    const float* imgb = img + (size_t)b  * (NC_IMG * HW_) + hw0;

    if (umb) {
        for (int c0 = 0; c0 < NC_MEM; c0 += 4) {
            int c = c0 + cb;
            xb[0][c][px] = memb[c * HW_ + px];
        }
    }
    for (int c0 = 0; c0 < NC_IMG; c0 += 4) {
        int c = c0 + cb;
        xb[0][NC_MEM + c][px] = imgb[c * HW_ + px];
    }
    __syncthreads();

    // ---- FTL on channels 0..31 (only when memory used) ----
    if (umb) {
        float xf[16];
#pragma unroll
        for (int i = 0; i < 16; ++i) xf[i] = ws[XF_OFF + b * 16 + i];
        for (int item = t; item < 8 * P_TILE; item += 256) {
            int g = item >> 6, p = item & 63;
            float v0 = xb[0][4 * g + 0][p];
            float v1 = xb[0][4 * g + 1][p];
            float v2 = xb[0][4 * g + 2][p];
            float v3 = xb[0][4 * g + 3][p];
            float r0 = xf[0]  * v0 + xf[1]  * v1 + xf[2]  * v2 + xf[3]  * v3;
            float r1 = xf[4]  * v0 + xf[5]  * v1 + xf[6]  * v2 + xf[7]  * v3;
            float r2 = xf[8]  * v0 + xf[9]  * v1 + xf[10] * v2 + xf[11] * v3;
            float r3 = xf[12] * v0 + xf[13] * v1 + xf[14] * v2 + xf[15] * v3;
            xb[0][4 * g + 0][p] = r0;
            xb[0][4 * g + 1][p] = r1;
            xb[0][4 * g + 2][p] = r2;
            xb[0][4 * g + 3][p] = r3;
        }
    }
    __syncthreads();

    const int ty = t >> 4;   // 0..15
    const int tx = t & 15;   // 0..15
    const int ob = ty * 8;   // output-channel base (layers 0,1)
    const int pb = tx * 4;   // pixel base

    // ---- layers 0 and 1: full 128 outputs, ReLU, ping-pong LDS ----
#pragma unroll
    for (int l = 0; l < 2; ++l) {
        const float* Wl = Wt + l * NC * NC;
        const float* bl = bs + l * NC;
        const float (*src)[P_TILE] = xb[l];
        float (*dst)[P_TILE] = xb[l ^ 1];

        float acc[8][4];
#pragma unroll
        for (int i = 0; i < 8; ++i) {
            float bi = bl[ob + i];
#pragma unroll
            for (int j = 0; j < 4; ++j) acc[i][j] = bi;
        }
        // layer 0 with no memory: channels 0..63 are zero -> skip
        const int c0 = (l == 0 && !umb) ? NC_MEM : 0;
#pragma unroll 8
        for (int c = c0; c < NC; ++c) {
            const float4 xv = *(const float4*)&src[c][pb];
            const float4 w0 = *(const float4*)&Wl[c * NC + ob];
            const float4 w1 = *(const float4*)&Wl[c * NC + ob + 4];
            const float xs[4] = {xv.x, xv.y, xv.z, xv.w};
            const float wv[8] = {w0.x, w0.y, w0.z, w0.w, w1.x, w1.y, w1.z, w1.w};
#pragma unroll
            for (int i = 0; i < 8; ++i)
#pragma unroll
                for (int j = 0; j < 4; ++j)
                    acc[i][j] += wv[i] * xs[j];
        }
#pragma unroll
        for (int i = 0; i < 8; ++i) {
            float4 v;
            v.x = fmaxf(acc[i][0], 0.f);
            v.y = fmaxf(acc[i][1], 0.f);
            v.z = fmaxf(acc[i][2], 0.f);
            v.w = fmaxf(acc[i][3], 0.f);
            *(float4*)&dst[ob + i][pb] = v;
        }
        __syncthreads();
    }

    // ---- layer 2: only outputs 64..127, write straight to global ----
    {
        const float* Wl = Wt + 2 * NC * NC;
        const float* bl = bs + 2 * NC;
        const int ob2 = NC_MEM + ty * 4; // 64..124

        float acc[4][4];
#pragma unroll
        for (int i = 0; i < 4; ++i) {
            float bi = bl[ob2 + i];
#pragma unroll
            for (int j = 0; j < 4; ++j) acc[i][j] = bi;
        }
#pragma unroll 8
        for (int c = 0; c < NC; ++c) {
            const float4 xv = *(const float4*)&xb[0][c][pb];
            const float4 w  = *(const float4*)&Wl[c * NC + ob2];
            const float xs[4] = {xv.x, xv.y, xv.z, xv.w};
            const float wv[4] = {w.x, w.y, w.z, w.w};
#pragma unroll
            for (int i = 0; i < 4; ++i)
#pragma unroll
                for (int j = 0; j < 4; ++j)
                    acc[i][j] += wv[i] * xs[j];
        }
        float* outb = out + ((size_t)b * NC_MEM + (ob2 - NC_MEM)) * HW_ + hw0 + pb;
#pragma unroll
        for (int i = 0; i < 4; ++i) {
            float4 v;
            v.x = acc[i][0]; v.y = acc[i][1]; v.z = acc[i][2]; v.w = acc[i][3];
            *(float4*)&outb[(size_t)i * HW_] = v;
        }
    }
}

extern "C" void kernel_launch(void* const* d_in, const int* in_sizes, int n_in,
                              void* d_out, int out_size, void* d_ws, size_t ws_size,
                              hipStream_t stream) {
    const float* img  = (const float*)d_in[0];
    const float* mem  = (const float*)d_in[1];
    const float* pext = (const float*)d_in[2];
    const float* cext = (const float*)d_in[3];
    const int*   midx = (const int*)d_in[4];
    const unsigned char* umem = (const unsigned char*)d_in[5];
    const float* Ws   = (const float*)d_in[6];
    const float* bs   = (const float*)d_in[7];
    float* out = (float*)d_out;
    float* ws  = (float*)d_ws;

    hipLaunchKernelGGL(prep_xf, dim3(1), dim3(64), 0, stream,
                       pext, cext, midx, umem, ws);
    hipLaunchKernelGGL(transpose_w, dim3(192), dim3(256), 0, stream, Ws, ws);
    hipLaunchKernelGGL(fused_main, dim3(NTILES, B_), dim3(256), 0, stream,
                       img, mem, midx, bs, ws, out);
}

// Round 2
// 183.988 us; speedup vs baseline: 2.0589x; 2.0589x over previous
//
#include <hip/hip_runtime.h>

#define NC_MEM 64
#define NC_IMG 64
#define NC     128
#define B_     32
#define H_     64
#define W_     96
#define HW_    (H_ * W_)      // 6144
#define P_TILE 64
#define NTILES (HW_ / P_TILE) // 96
#define RS     144            // LDS row stride in ushorts (128 + 16 pad -> 72 dwords, bank-balanced)

// d_ws byte layout
#define WA_HI  0                       // ushort[3][8][4][64][8] = 98304 B (bf16 hi, A-fragment order)
#define WA_LO  98304                   // same, bf16 lo
#define XF_OFF 196608                  // float[32][16]
#define UM_OFF 198656                  // float[32]

typedef __attribute__((ext_vector_type(8))) short bf16x8;
typedef __attribute__((ext_vector_type(4))) float f32x4;

__device__ inline unsigned short f2bf(float x) {
    unsigned u = __float_as_uint(x);
    return (unsigned short)((u + 0x7FFFu + ((u >> 16) & 1u)) >> 16);
}
__device__ inline float bf2f(unsigned short h) {
    return __uint_as_float(((unsigned)h) << 16);
}

// ---------------------------------------------------------------------------
// prep_xf: per-batch 4x4 inverse + xf = cur @ inv(safe_prev); decode use_memory
// (runtime bool-vs-int32 detection).
// ---------------------------------------------------------------------------
__global__ void prep_xf(const float* __restrict__ prev_ext,
                        const float* __restrict__ cur_ext,
                        const int* __restrict__ mem_idx,
                        const unsigned char* __restrict__ um_raw,
                        unsigned char* __restrict__ wsb) {
    int b = threadIdx.x;
    if (b >= B_) return;

    bool is_bool = false;
    for (int i = 0; i < 32; ++i)
        if ((i & 3) && um_raw[i]) is_bool = true;
    bool um = is_bool ? (um_raw[b] != 0) : (((const int*)um_raw)[b] != 0);

    int mi = mem_idx[b];
    float A[4][4], inv[4][4];
    for (int i = 0; i < 4; ++i)
        for (int j = 0; j < 4; ++j) {
            A[i][j]   = um ? prev_ext[mi * 16 + i * 4 + j] : (i == j ? 1.f : 0.f);
            inv[i][j] = (i == j) ? 1.f : 0.f;
        }
    for (int col = 0; col < 4; ++col) {
        int piv = col; float best = fabsf(A[col][col]);
        for (int r = col + 1; r < 4; ++r) {
            float v = fabsf(A[r][col]);
            if (v > best) { best = v; piv = r; }
        }
        if (piv != col)
            for (int j = 0; j < 4; ++j) {
                float t = A[col][j]; A[col][j] = A[piv][j]; A[piv][j] = t;
                t = inv[col][j]; inv[col][j] = inv[piv][j]; inv[piv][j] = t;
            }
        float d = 1.0f / A[col][col];
        for (int j = 0; j < 4; ++j) { A[col][j] *= d; inv[col][j] *= d; }
        for (int r = 0; r < 4; ++r) {
            if (r == col) continue;
            float f = A[r][col];
            for (int j = 0; j < 4; ++j) {
                A[r][j] -= f * A[col][j];
                inv[r][j] -= f * inv[col][j];
            }
        }
    }
    float* xf = (float*)(wsb + XF_OFF) + b * 16;
    for (int i = 0; i < 4; ++i)
        for (int j = 0; j < 4; ++j) {
            float s = 0.f;
            for (int k = 0; k < 4; ++k)
                s += cur_ext[b * 16 + i * 4 + k] * inv[k][j];
            xf[i * 4 + j] = s;
        }
    ((float*)(wsb + UM_OFF))[b] = um ? 1.f : 0.f;
}

// ---------------------------------------------------------------------------
// prep_w: split W into bf16 hi/lo, stored in MFMA A-fragment order:
//   frag[l][mt][ks][lane][j] = W[l][o = mt*16 + (lane&15)][c = ks*32 + (lane>>4)*8 + j]
// ---------------------------------------------------------------------------
__global__ void prep_w(const float* __restrict__ Ws, unsigned char* __restrict__ wsb) {
    int idx = blockIdx.x * 256 + threadIdx.x;
    if (idx >= 3 * NC * NC) return;
    int l = idx >> 14, r = idx & 16383, o = r >> 7, c = r & 127;
    float w = Ws[idx];
    unsigned short hi = f2bf(w);
    unsigned short lo = f2bf(w - bf2f(hi));
    int mt = o >> 4, lm = o & 15, ks = c >> 5, kr = c & 31, q = kr >> 3, j = kr & 7;
    int lane = q * 16 + lm;
    int di = ((((l * 8 + mt) * 4 + ks) * 64 + lane) << 3) + j;
    ((unsigned short*)(wsb + WA_HI))[di] = hi;
    ((unsigned short*)(wsb + WA_LO))[di] = lo;
}

// ---------------------------------------------------------------------------
// fused_main: stage x (FTL + bf16 hi/lo) into LDS, 3 layers of split-bf16 MFMA.
// Wave w: layers 0/1 -> m-tiles {2w,2w+1} x n-tiles 0..3; layer 2 -> m-tile 4+w.
// ---------------------------------------------------------------------------
__global__ __launch_bounds__(256)
void fused_main(const float* __restrict__ img, const float* __restrict__ mem,
                const int* __restrict__ mem_idx, const float* __restrict__ bs,
                const unsigned char* __restrict__ wsb, float* __restrict__ out) {
    __shared__ unsigned short xh[64 * RS]; // 18432 B
    __shared__ unsigned short xl[64 * RS]; // 18432 B

    const int t   = threadIdx.x;
    const int b   = blockIdx.y;
    const int hw0 = blockIdx.x * P_TILE;
    const bool umb = ((const float*)(wsb + UM_OFF))[b] != 0.f;
    const int mi  = mem_idx[b];

    const bf16x8* __restrict__ WH = (const bf16x8*)(wsb + WA_HI);
    const bf16x8* __restrict__ WL = (const bf16x8*)(wsb + WA_LO);

    // ---- stage: global f32 -> (FTL) -> bf16 hi/lo in LDS ----
    {
        const int px = t & 63, cq = t >> 6;
        float xfv[16];
        if (umb) {
            const float* xfp = (const float*)(wsb + XF_OFF) + b * 16;
#pragma unroll
            for (int i = 0; i < 16; ++i) xfv[i] = xfp[i];
        }
        const int pstart = umb ? 0 : 4;
        for (int p = pstart; p < 8; ++p) {
            int gg = p * 4 + cq;       // 0..31
            int c0 = gg * 4;
            const float* src = (c0 < 64)
                ? (mem + ((size_t)mi * 64 + c0) * HW_ + hw0 + px)
                : (img + ((size_t)b  * 64 + (c0 - 64)) * HW_ + hw0 + px);
            float v[4];
            v[0] = src[0]; v[1] = src[HW_]; v[2] = src[2 * HW_]; v[3] = src[3 * HW_];
            if (umb && gg < 8) {
                float r0 = xfv[0]  * v[0] + xfv[1]  * v[1] + xfv[2]  * v[2] + xfv[3]  * v[3];
                float r1 = xfv[4]  * v[0] + xfv[5]  * v[1] + xfv[6]  * v[2] + xfv[7]  * v[3];
                float r2 = xfv[8]  * v[0] + xfv[9]  * v[1] + xfv[10] * v[2] + xfv[11] * v[3];
                float r3 = xfv[12] * v[0] + xfv[13] * v[1] + xfv[14] * v[2] + xfv[15] * v[3];
                v[0] = r0; v[1] = r1; v[2] = r2; v[3] = r3;
            }
            unsigned hs[4], ls[4];
#pragma unroll
            for (int i = 0; i < 4; ++i) {
                hs[i] = f2bf(v[i]);
                ls[i] = f2bf(v[i] - bf2f((unsigned short)hs[i]));
            }
            uint2 hp = make_uint2(hs[0] | (hs[1] << 16), hs[2] | (hs[3] << 16));
            uint2 lp = make_uint2(ls[0] | (ls[1] << 16), ls[2] | (ls[3] << 16));
            *(uint2*)&xh[px * RS + c0] = hp;
            *(uint2*)&xl[px * RS + c0] = lp;
        }
    }
    __syncthreads();

    const int w    = t >> 6;
    const int lane = t & 63;
    const int q    = lane >> 4;
    const int lm   = lane & 15;

    // ---- layers 0,1: full 128 outputs, ReLU, write back to LDS ----
    const int mt0 = 2 * w;
#pragma unroll
    for (int l = 0; l < 2; ++l) {
        f32x4 acc[2][4];
#pragma unroll
        for (int mi2 = 0; mi2 < 2; ++mi2) {
            f32x4 bv = *(const f32x4*)&bs[l * NC + (mt0 + mi2) * 16 + q * 4];
#pragma unroll
            for (int nt = 0; nt < 4; ++nt) acc[mi2][nt] = bv;
        }
        const int ks0 = (l == 0 && !umb) ? 2 : 0;
        for (int ks = ks0; ks < 4; ++ks) {
            int f0 = ((l * 8 + mt0) * 4 + ks) * 64 + lane;
            int f1 = ((l * 8 + mt0 + 1) * 4 + ks) * 64 + lane;
            bf16x8 ah0 = WH[f0], al0 = WL[f0];
            bf16x8 ah1 = WH[f1], al1 = WL[f1];
#pragma unroll
            for (int nt = 0; nt < 4; ++nt) {
                bf16x8 bh = *(const bf16x8*)&xh[(nt * 16 + lm) * RS + ks * 32 + q * 8];
                bf16x8 bl = *(const bf16x8*)&xl[(nt * 16 + lm) * RS + ks * 32 + q * 8];
                acc[0][nt] = __builtin_amdgcn_mfma_f32_16x16x32_bf16(ah0, bh, acc[0][nt], 0, 0, 0);
                acc[1][nt] = __builtin_amdgcn_mfma_f32_16x16x32_bf16(ah1, bh, acc[1][nt], 0, 0, 0);
                acc[0][nt] = __builtin_amdgcn_mfma_f32_16x16x32_bf16(al0, bh, acc[0][nt], 0, 0, 0);
                acc[1][nt] = __builtin_amdgcn_mfma_f32_16x16x32_bf16(al1, bh, acc[1][nt], 0, 0, 0);
                acc[0][nt] = __builtin_amdgcn_mfma_f32_16x16x32_bf16(ah0, bl, acc[0][nt], 0, 0, 0);
                acc[1][nt] = __builtin_amdgcn_mfma_f32_16x16x32_bf16(ah1, bl, acc[1][nt], 0, 0, 0);
            }
        }
        __syncthreads(); // all reads of x done before overwrite
#pragma unroll
        for (int mi2 = 0; mi2 < 2; ++mi2) {
            int o0 = (mt0 + mi2) * 16 + q * 4;
#pragma unroll
            for (int nt = 0; nt < 4; ++nt) {
                int ppx = nt * 16 + lm;
                unsigned hs[4], ls[4];
#pragma unroll
                for (int r = 0; r < 4; ++r) {
                    float v = fmaxf(acc[mi2][nt][r], 0.f);
                    hs[r] = f2bf(v);
                    ls[r] = f2bf(v - bf2f((unsigned short)hs[r]));
                }
                *(uint2*)&xh[ppx * RS + o0] = make_uint2(hs[0] | (hs[1] << 16), hs[2] | (hs[3] << 16));
                *(uint2*)&xl[ppx * RS + o0] = make_uint2(ls[0] | (ls[1] << 16), ls[2] | (ls[3] << 16));
            }
        }
        __syncthreads();
    }

    // ---- layer 2: out channels 64..127 only, straight to global ----
    {
        const int mt2 = 4 + w;
        f32x4 acc[4];
        f32x4 bv = *(const f32x4*)&bs[2 * NC + mt2 * 16 + q * 4];
#pragma unroll
        for (int nt = 0; nt < 4; ++nt) acc[nt] = bv;
#pragma unroll
        for (int ks = 0; ks < 4; ++ks) {
            int f = ((2 * 8 + mt2) * 4 + ks) * 64 + lane;
            bf16x8 ah = WH[f], al = WL[f];
#pragma unroll
            for (int nt = 0; nt < 4; ++nt) {
                bf16x8 bh = *(const bf16x8*)&xh[(nt * 16 + lm) * RS + ks * 32 + q * 8];
                bf16x8 bl = *(const bf16x8*)&xl[(nt * 16 + lm) * RS + ks * 32 + q * 8];
                acc[nt] = __builtin_amdgcn_mfma_f32_16x16x32_bf16(ah, bh, acc[nt], 0, 0, 0);
                acc[nt] = __builtin_amdgcn_mfma_f32_16x16x32_bf16(al, bh, acc[nt], 0, 0, 0);
                acc[nt] = __builtin_amdgcn_mfma_f32_16x16x32_bf16(ah, bl, acc[nt], 0, 0, 0);
            }
        }
        const int oc0 = mt2 * 16 + q * 4 - 64; // 0..63
#pragma unroll
        for (int nt = 0; nt < 4; ++nt) {
            float* dst = out + ((size_t)b * 64 + oc0) * HW_ + hw0 + nt * 16 + lm;
#pragma unroll
            for (int r = 0; r < 4; ++r)
                dst[(size_t)r * HW_] = acc[nt][r];
        }
    }
}

extern "C" void kernel_launch(void* const* d_in, const int* in_sizes, int n_in,
                              void* d_out, int out_size, void* d_ws, size_t ws_size,
                              hipStream_t stream) {
    const float* img  = (const float*)d_in[0];
    const float* mem  = (const float*)d_in[1];
    const float* pext = (const float*)d_in[2];
    const float* cext = (const float*)d_in[3];
    const int*   midx = (const int*)d_in[4];
    const unsigned char* umem = (const unsigned char*)d_in[5];
    const float* Ws   = (const float*)d_in[6];
    const float* bs   = (const float*)d_in[7];
    float* out = (float*)d_out;
    unsigned char* wsb = (unsigned char*)d_ws;

    hipLaunchKernelGGL(prep_xf, dim3(1), dim3(64), 0, stream, pext, cext, midx, umem, wsb);
    hipLaunchKernelGGL(prep_w, dim3(192), dim3(256), 0, stream, Ws, wsb);
    hipLaunchKernelGGL(fused_main, dim3(NTILES, B_), dim3(256), 0, stream,
                       img, mem, midx, bs, wsb, out);
}

// Round 3
// 175.852 us; speedup vs baseline: 2.1542x; 1.0463x over previous
//
#include <hip/hip_runtime.h>

#define NC_MEM 64
#define NC_IMG 64
#define NC     128
#define B_     32
#define H_     64
#define W_     96
#define HW_    (H_ * W_)      // 6144
#define P_TILE 64
#define NTILES (HW_ / P_TILE) // 96
#define RS     136            // LDS row stride in ushorts: 68 dwords ≡ 4 (mod 32) -> bank-uniform

// d_ws byte layout
#define WA_HI  0                       // ushort[3][8][4][64][8] = 98304 B (bf16 hi, A-fragment order)
#define WA_LO  98304                   // same, bf16 lo
#define XF_OFF 196608                  // float[32][16]
#define UM_OFF 198656                  // float[32]

typedef __attribute__((ext_vector_type(8))) short bf16x8;
typedef __attribute__((ext_vector_type(4))) float f32x4;

__device__ inline unsigned short f2bf_rn(float x) {
    unsigned u = __float_as_uint(x);
    return (unsigned short)((u + 0x7FFFu + ((u >> 16) & 1u)) >> 16);
}
__device__ inline float bf2f(unsigned short h) {
    return __uint_as_float(((unsigned)h) << 16);
}

// ---------------------------------------------------------------------------
// prep (merged): blocks 0..191 split W into bf16 hi/lo in MFMA A-fragment
// order; block 192 computes xf = cur @ inv(safe_prev) via closed-form adjugate
// (static indexing only — the R2 Gauss-Jordan ran from scratch memory and cost
// ~70 us on a single workgroup) and decodes use_memory.
// ---------------------------------------------------------------------------
__global__ void prep(const float* __restrict__ Ws,
                     const float* __restrict__ prev_ext,
                     const float* __restrict__ cur_ext,
                     const int* __restrict__ mem_idx,
                     const unsigned char* __restrict__ um_raw,
                     unsigned char* __restrict__ wsb) {
    if (blockIdx.x < 192) {
        int idx = blockIdx.x * 256 + threadIdx.x;   // < 49152 = 3*128*128
        int l = idx >> 14, r = idx & 16383, o = r >> 7, c = r & 127;
        float w = Ws[idx];
        unsigned short hi = f2bf_rn(w);
        unsigned short lo = f2bf_rn(w - bf2f(hi));
        int mt = o >> 4, lm = o & 15, ks = c >> 5, kr = c & 31, q = kr >> 3, j = kr & 7;
        int lane = q * 16 + lm;
        int di = ((((l * 8 + mt) * 4 + ks) * 64 + lane) << 3) + j;
        ((unsigned short*)(wsb + WA_HI))[di] = hi;
        ((unsigned short*)(wsb + WA_LO))[di] = lo;
        return;
    }
    int b = threadIdx.x;
    if (b >= B_) return;

    bool is_bool = false;
    for (int i = 0; i < 32; ++i)
        if ((i & 3) && um_raw[i]) is_bool = true;
    bool um = is_bool ? (um_raw[b] != 0) : (((const int*)um_raw)[b] != 0);
    int mi = mem_idx[b];

    float a[16];
#pragma unroll
    for (int i = 0; i < 16; ++i)
        a[i] = um ? prev_ext[mi * 16 + i] : ((i % 5 == 0) ? 1.f : 0.f);

    // closed-form 4x4 inverse (row-major), Laplace 2x2 expansion
    float s0 = a[0]*a[5]  - a[1]*a[4];
    float s1 = a[0]*a[6]  - a[2]*a[4];
    float s2 = a[0]*a[7]  - a[3]*a[4];
    float s3 = a[1]*a[6]  - a[2]*a[5];
    float s4 = a[1]*a[7]  - a[3]*a[5];
    float s5 = a[2]*a[7]  - a[3]*a[6];
    float c5 = a[10]*a[15] - a[11]*a[14];
    float c4 = a[9]*a[15]  - a[11]*a[13];
    float c3 = a[9]*a[14]  - a[10]*a[13];
    float c2 = a[8]*a[15]  - a[11]*a[12];
    float c1 = a[8]*a[14]  - a[10]*a[12];
    float c0 = a[8]*a[13]  - a[9]*a[12];
    float det = s0*c5 - s1*c4 + s2*c3 + s3*c2 - s4*c1 + s5*c0;
    float id = 1.0f / det;

    float inv[16];
    inv[0]  = ( a[5]*c5  - a[6]*c4  + a[7]*c3)  * id;
    inv[1]  = (-a[1]*c5  + a[2]*c4  - a[3]*c3)  * id;
    inv[2]  = ( a[13]*s5 - a[14]*s4 + a[15]*s3) * id;
    inv[3]  = (-a[9]*s5  + a[10]*s4 - a[11]*s3) * id;
    inv[4]  = (-a[4]*c5  + a[6]*c2  - a[7]*c1)  * id;
    inv[5]  = ( a[0]*c5  - a[2]*c2  + a[3]*c1)  * id;
    inv[6]  = (-a[12]*s5 + a[14]*s2 - a[15]*s1) * id;
    inv[7]  = ( a[8]*s5  - a[10]*s2 + a[11]*s1) * id;
    inv[8]  = ( a[4]*c4  - a[5]*c2  + a[7]*c0)  * id;
    inv[9]  = (-a[0]*c4  + a[1]*c2  - a[3]*c0)  * id;
    inv[10] = ( a[12]*s4 - a[13]*s2 + a[15]*s0) * id;
    inv[11] = (-a[8]*s4  + a[9]*s2  - a[11]*s0) * id;
    inv[12] = (-a[4]*c3  + a[5]*c1  - a[6]*c0)  * id;
    inv[13] = ( a[0]*c3  - a[1]*c1  + a[2]*c0)  * id;
    inv[14] = (-a[12]*s3 + a[13]*s1 - a[14]*s0) * id;
    inv[15] = ( a[8]*s3  - a[9]*s1  + a[10]*s0) * id;

    float* xf = (float*)(wsb + XF_OFF) + b * 16;
#pragma unroll
    for (int i = 0; i < 4; ++i)
#pragma unroll
        for (int j2 = 0; j2 < 4; ++j2) {
            float s = 0.f;
#pragma unroll
            for (int k = 0; k < 4; ++k)
                s += cur_ext[b * 16 + i * 4 + k] * inv[k * 4 + j2];
            xf[i * 4 + j2] = s;
        }
    ((float*)(wsb + UM_OFF))[b] = um ? 1.f : 0.f;
}

// ---------------------------------------------------------------------------
// fused_main: stage x (FTL + truncation bf16 hi/lo) into LDS, 3 layers of
// split-bf16 MFMA (hi*hi + lo*hi + hi*lo). RS=136 -> bank-uniform LDS.
// ---------------------------------------------------------------------------
__global__ __launch_bounds__(256, 4)
void fused_main(const float* __restrict__ img, const float* __restrict__ mem,
                const int* __restrict__ mem_idx, const float* __restrict__ bs,
                const unsigned char* __restrict__ wsb, float* __restrict__ out) {
    __shared__ unsigned short xh[64 * RS]; // 17408 B
    __shared__ unsigned short xl[64 * RS]; // 17408 B

    const int t   = threadIdx.x;
    const int b   = blockIdx.y;
    const int hw0 = blockIdx.x * P_TILE;
    const bool umb = ((const float*)(wsb + UM_OFF))[b] != 0.f;
    const int mi  = mem_idx[b];

    const bf16x8* __restrict__ WH = (const bf16x8*)(wsb + WA_HI);
    const bf16x8* __restrict__ WL = (const bf16x8*)(wsb + WA_LO);

    // ---- stage: global f32 -> (FTL) -> truncation-split bf16 hi/lo in LDS ----
    {
        const int px = t & 63, cq = t >> 6;
        float xfv[16];
        if (umb) {
            const float* xfp = (const float*)(wsb + XF_OFF) + b * 16;
#pragma unroll
            for (int i = 0; i < 16; ++i) xfv[i] = xfp[i];
        }
        const int pstart = umb ? 0 : 4;
        for (int p = pstart; p < 8; ++p) {
            int gg = p * 4 + cq;       // channel group 0..31
            int c0 = gg * 4;
            const float* src = (c0 < 64)
                ? (mem + ((size_t)mi * 64 + c0) * HW_ + hw0 + px)
                : (img + ((size_t)b  * 64 + (c0 - 64)) * HW_ + hw0 + px);
            float v0 = src[0], v1 = src[HW_], v2 = src[2 * HW_], v3 = src[3 * HW_];
            if (umb && gg < 8) {
                float r0 = xfv[0]  * v0 + xfv[1]  * v1 + xfv[2]  * v2 + xfv[3]  * v3;
                float r1 = xfv[4]  * v0 + xfv[5]  * v1 + xfv[6]  * v2 + xfv[7]  * v3;
                float r2 = xfv[8]  * v0 + xfv[9]  * v1 + xfv[10] * v2 + xfv[11] * v3;
                float r3 = xfv[12] * v0 + xfv[13] * v1 + xfv[14] * v2 + xfv[15] * v3;
                v0 = r0; v1 = r1; v2 = r2; v3 = r3;
            }
            unsigned u0 = __float_as_uint(v0), u1 = __float_as_uint(v1);
            unsigned u2 = __float_as_uint(v2), u3 = __float_as_uint(v3);
            unsigned l0 = __float_as_uint(v0 - __uint_as_float(u0 & 0xFFFF0000u));
            unsigned l1 = __float_as_uint(v1 - __uint_as_float(u1 & 0xFFFF0000u));
            unsigned l2 = __float_as_uint(v2 - __uint_as_float(u2 & 0xFFFF0000u));
            unsigned l3 = __float_as_uint(v3 - __uint_as_float(u3 & 0xFFFF0000u));
            uint2 hp = make_uint2(__builtin_amdgcn_perm(u1, u0, 0x07060302u),
                                  __builtin_amdgcn_perm(u3, u2, 0x07060302u));
            uint2 lp = make_uint2(__builtin_amdgcn_perm(l1, l0, 0x07060302u),
                                  __builtin_amdgcn_perm(l3, l2, 0x07060302u));
            *(uint2*)&xh[px * RS + c0] = hp;
            *(uint2*)&xl[px * RS + c0] = lp;
        }
    }
    __syncthreads();

    const int w    = t >> 6;
    const int lane = t & 63;
    const int q    = lane >> 4;
    const int lm   = lane & 15;

    // ---- layers 0,1: full 128 outputs, ReLU, write back to LDS ----
    const int mt0 = 2 * w;
#pragma unroll
    for (int l = 0; l < 2; ++l) {
        f32x4 acc[2][4];
#pragma unroll
        for (int mi2 = 0; mi2 < 2; ++mi2) {
            f32x4 bv = *(const f32x4*)&bs[l * NC + (mt0 + mi2) * 16 + q * 4];
#pragma unroll
            for (int nt = 0; nt < 4; ++nt) acc[mi2][nt] = bv;
        }
        auto do_ks = [&](int ks) {
            int f0 = ((l * 8 + mt0) * 4 + ks) * 64 + lane;
            int f1 = ((l * 8 + mt0 + 1) * 4 + ks) * 64 + lane;
            bf16x8 ah0 = WH[f0], al0 = WL[f0];
            bf16x8 ah1 = WH[f1], al1 = WL[f1];
#pragma unroll
            for (int nt = 0; nt < 4; ++nt) {
                bf16x8 bh = *(const bf16x8*)&xh[(nt * 16 + lm) * RS + ks * 32 + q * 8];
                bf16x8 bl = *(const bf16x8*)&xl[(nt * 16 + lm) * RS + ks * 32 + q * 8];
                acc[0][nt] = __builtin_amdgcn_mfma_f32_16x16x32_bf16(ah0, bh, acc[0][nt], 0, 0, 0);
                acc[1][nt] = __builtin_amdgcn_mfma_f32_16x16x32_bf16(ah1, bh, acc[1][nt], 0, 0, 0);
                acc[0][nt] = __builtin_amdgcn_mfma_f32_16x16x32_bf16(al0, bh, acc[0][nt], 0, 0, 0);
                acc[1][nt] = __builtin_amdgcn_mfma_f32_16x16x32_bf16(al1, bh, acc[1][nt], 0, 0, 0);
                acc[0][nt] = __builtin_amdgcn_mfma_f32_16x16x32_bf16(ah0, bl, acc[0][nt], 0, 0, 0);
                acc[1][nt] = __builtin_amdgcn_mfma_f32_16x16x32_bf16(ah1, bl, acc[1][nt], 0, 0, 0);
            }
        };
        if (l == 0 && !umb) { do_ks(2); do_ks(3); }
        else { do_ks(0); do_ks(1); do_ks(2); do_ks(3); }

        __syncthreads(); // all reads of x done before overwrite
#pragma unroll
        for (int mi2 = 0; mi2 < 2; ++mi2) {
            int o0 = (mt0 + mi2) * 16 + q * 4;
#pragma unroll
            for (int nt = 0; nt < 4; ++nt) {
                int ppx = nt * 16 + lm;
                float v0 = fmaxf(acc[mi2][nt][0], 0.f);
                float v1 = fmaxf(acc[mi2][nt][1], 0.f);
                float v2 = fmaxf(acc[mi2][nt][2], 0.f);
                float v3 = fmaxf(acc[mi2][nt][3], 0.f);
                unsigned u0 = __float_as_uint(v0), u1 = __float_as_uint(v1);
                unsigned u2 = __float_as_uint(v2), u3 = __float_as_uint(v3);
                unsigned l0 = __float_as_uint(v0 - __uint_as_float(u0 & 0xFFFF0000u));
                unsigned l1 = __float_as_uint(v1 - __uint_as_float(u1 & 0xFFFF0000u));
                unsigned l2 = __float_as_uint(v2 - __uint_as_float(u2 & 0xFFFF0000u));
                unsigned l3 = __float_as_uint(v3 - __uint_as_float(u3 & 0xFFFF0000u));
                *(uint2*)&xh[ppx * RS + o0] =
                    make_uint2(__builtin_amdgcn_perm(u1, u0, 0x07060302u),
                               __builtin_amdgcn_perm(u3, u2, 0x07060302u));
                *(uint2*)&xl[ppx * RS + o0] =
                    make_uint2(__builtin_amdgcn_perm(l1, l0, 0x07060302u),
                               __builtin_amdgcn_perm(l3, l2, 0x07060302u));
            }
        }
        __syncthreads();
    }

    // ---- layer 2: out channels 64..127 only, straight to global ----
    {
        const int mt2 = 4 + w;
        f32x4 acc[4];
        f32x4 bv = *(const f32x4*)&bs[2 * NC + mt2 * 16 + q * 4];
#pragma unroll
        for (int nt = 0; nt < 4; ++nt) acc[nt] = bv;
#pragma unroll
        for (int ks = 0; ks < 4; ++ks) {
            int f = ((2 * 8 + mt2) * 4 + ks) * 64 + lane;
            bf16x8 ah = WH[f], al = WL[f];
#pragma unroll
            for (int nt = 0; nt < 4; ++nt) {
                bf16x8 bh = *(const bf16x8*)&xh[(nt * 16 + lm) * RS + ks * 32 + q * 8];
                bf16x8 bl = *(const bf16x8*)&xl[(nt * 16 + lm) * RS + ks * 32 + q * 8];
                acc[nt] = __builtin_amdgcn_mfma_f32_16x16x32_bf16(ah, bh, acc[nt], 0, 0, 0);
                acc[nt] = __builtin_amdgcn_mfma_f32_16x16x32_bf16(al, bh, acc[nt], 0, 0, 0);
                acc[nt] = __builtin_amdgcn_mfma_f32_16x16x32_bf16(ah, bl, acc[nt], 0, 0, 0);
            }
        }
        const int oc0 = mt2 * 16 + q * 4 - 64; // 0..63
#pragma unroll
        for (int nt = 0; nt < 4; ++nt) {
            float* dst = out + ((size_t)b * 64 + oc0) * HW_ + hw0 + nt * 16 + lm;
#pragma unroll
            for (int r = 0; r < 4; ++r)
                dst[(size_t)r * HW_] = acc[nt][r];
        }
    }
}

extern "C" void kernel_launch(void* const* d_in, const int* in_sizes, int n_in,
                              void* d_out, int out_size, void* d_ws, size_t ws_size,
                              hipStream_t stream) {
    const float* img  = (const float*)d_in[0];
    const float* mem  = (const float*)d_in[1];
    const float* pext = (const float*)d_in[2];
    const float* cext = (const float*)d_in[3];
    const int*   midx = (const int*)d_in[4];
    const unsigned char* umem = (const unsigned char*)d_in[5];
    const float* Ws   = (const float*)d_in[6];
    const float* bs   = (const float*)d_in[7];
    float* out = (float*)d_out;
    unsigned char* wsb = (unsigned char*)d_ws;

    hipLaunchKernelGGL(prep, dim3(193), dim3(256), 0, stream,
                       Ws, pext, cext, midx, umem, wsb);
    hipLaunchKernelGGL(fused_main, dim3(NTILES, B_), dim3(256), 0, stream,
                       img, mem, midx, bs, wsb, out);
}